// Round 1
// baseline (1900.391 us; speedup 1.0000x reference)
//
#include <hip/hip_runtime.h>
#include <hip/hip_bf16.h>

// Problem constants (fixed by setup_inputs)
#define BATCH 512
#define HDIM  1024
#define G4    4096   // 4*H
#define DSTEP 64
#define NOUT  512

typedef __bf16 bf16;
typedef __bf16 bf16x8 __attribute__((ext_vector_type(8)));
typedef float  f32x4  __attribute__((ext_vector_type(4)));

#define MFMA16(a, b, c) __builtin_amdgcn_mfma_f32_16x16x32_bf16((a), (b), (c), 0, 0, 0)

__device__ __forceinline__ float sigmoid_f(float x) { return 1.0f / (1.0f + __expf(-x)); }
__device__ __forceinline__ float tanh_f(float x)    { return 1.0f - 2.0f / (__expf(2.0f * x) + 1.0f); }

// ---------------- prep: fp32 -> bf16 conversions + state init ----------------
__global__ void prep_kernel(const float* __restrict__ x, const float* __restrict__ h0,
                            const float* __restrict__ c0, const float* __restrict__ W_ih,
                            const float* __restrict__ W_hh, const float* __restrict__ W_out,
                            bf16* __restrict__ x_b, bf16* __restrict__ Wih_b,
                            bf16* __restrict__ Whh_b, bf16* __restrict__ Wout_b,
                            bf16* __restrict__ h_slot0, float* __restrict__ c) {
    int tid = blockIdx.x * blockDim.x + threadIdx.x;
    int stride = gridDim.x * blockDim.x;
    for (int i = tid; i < G4 * HDIM; i += stride) {
        Whh_b[i] = (bf16)W_hh[i];
        Wih_b[i] = (bf16)W_ih[i];
    }
    for (int i = tid; i < BATCH * HDIM; i += stride) {
        x_b[i]    = (bf16)x[i];
        Wout_b[i] = (bf16)W_out[i];  // W_out is (512,1024) = 524288 elems, same count
        h_slot0[i] = (bf16)h0[i];
        c[i] = c0[i];
    }
}

// ---------------- generic C = A @ B^T + bias (bf16 in, f32 out) ----------------
// A: (M,K) row-major bf16; Bw: (N,K) row-major bf16; C: (M,N) f32. 1 wave per 32x32 tile.
template <int M, int N, int K>
__global__ __launch_bounds__(64) void gemm_bt(const bf16* __restrict__ A,
                                              const bf16* __restrict__ Bw,
                                              const float* __restrict__ bias,
                                              float* __restrict__ C) {
    constexpr int NT = N / 32;
    constexpr int MT = M / 32;
    constexpr int TOT = NT * MT;
    int bid = blockIdx.x;
    // XCD-chunked: each XCD gets a contiguous mt range (A-panel L2 reuse)
    int g = (bid & 7) * (TOT / 8) + (bid >> 3);
    int nt = g % NT, mt = g / NT;
    int l = threadIdx.x;
    int lr = l & 15, lk = (l >> 4) * 8;

    const bf16* Ap = A + (size_t)(mt * 32 + lr) * K + lk;
    const bf16* Bp = Bw + (size_t)(nt * 32 + lr) * K + lk;

    f32x4 acc[2][2] = {};
    for (int k0 = 0; k0 < K; k0 += 32) {
        bf16x8 a0 = *(const bf16x8*)(Ap + k0);
        bf16x8 a1 = *(const bf16x8*)(Ap + 16 * K + k0);
        bf16x8 b0 = *(const bf16x8*)(Bp + k0);
        bf16x8 b1 = *(const bf16x8*)(Bp + 16 * K + k0);
        acc[0][0] = MFMA16(a0, b0, acc[0][0]);
        acc[0][1] = MFMA16(a0, b1, acc[0][1]);
        acc[1][0] = MFMA16(a1, b0, acc[1][0]);
        acc[1][1] = MFMA16(a1, b1, acc[1][1]);
    }
    // C/D layout: col = lane&15, row = (lane>>4)*4 + r  [m89-verified]
    int r0 = mt * 32, cb = nt * 32;
    for (int fm = 0; fm < 2; ++fm)
        for (int fn = 0; fn < 2; ++fn) {
            int col = cb + fn * 16 + lr;
            float bs = bias[col];
            for (int r = 0; r < 4; ++r) {
                int row = r0 + fm * 16 + (l >> 4) * 4 + r;
                C[(size_t)row * N + col] = acc[fm][fn][r] + bs;
            }
        }
}

// ---------------- fused LSTM step ----------------
// WG = 256 threads = 4 waves: (bw in {0,1}) x (kw in {0,1}).
// Tile: 64 batch rows x 32 h cols, all 4 gates. Each wave: 32x32x4gates over half of K.
__global__ __launch_bounds__(256) void lstm_step(const bf16* __restrict__ h_prev,  // [512][1024]
                                                 const bf16* __restrict__ Whh,     // [4096][1024]
                                                 const float* __restrict__ xW,     // [512][4096]
                                                 const float* __restrict__ b_hh,   // [4096]
                                                 float* __restrict__ c,            // [512][1024]
                                                 bf16* __restrict__ h_out) {       // [512][1024]
    __shared__ float red[2 * 4096];  // [bw][gt*2+fm][fn][r][lane] flattened, 32 KB

    int bid = blockIdx.x;            // 256 blocks
    int xcd = bid & 7;
    int idx = bid >> 3;              // 0..31
    int ht = xcd * 4 + (idx >> 3);   // 0..31  (XCD-chunked h-column panels)
    int bt = idx & 7;                // 0..7

    int tid = threadIdx.x;
    int lane = tid & 63;
    int wid = tid >> 6;
    int bw = wid & 1, kw = wid >> 1;

    int b0 = bt * 64 + bw * 32;      // batch row base for this wave
    int h0 = ht * 32;                // h col base
    int lr = lane & 15, lk = (lane >> 4) * 8;

    const bf16* Ap = h_prev + (size_t)(b0 + lr) * HDIM + lk;
    const bf16* Bp = Whh + (size_t)(h0 + lr) * HDIM + lk;

    f32x4 acc[4][2][2] = {};
    int kbase = kw * (HDIM / 2);
    for (int ki = 0; ki < HDIM / 2; ki += 32) {
        int k0 = kbase + ki;
        bf16x8 a0 = *(const bf16x8*)(Ap + k0);
        bf16x8 a1 = *(const bf16x8*)(Ap + 16 * HDIM + k0);
        bf16x8 bfrag[4][2];
#pragma unroll
        for (int gt = 0; gt < 4; ++gt) {
#pragma unroll
            for (int fn = 0; fn < 2; ++fn)
                bfrag[gt][fn] = *(const bf16x8*)(Bp + (size_t)(gt * HDIM + fn * 16) * HDIM + k0);
        }
#pragma unroll
        for (int gt = 0; gt < 4; ++gt) {
            acc[gt][0][0] = MFMA16(a0, bfrag[gt][0], acc[gt][0][0]);
            acc[gt][0][1] = MFMA16(a0, bfrag[gt][1], acc[gt][0][1]);
            acc[gt][1][0] = MFMA16(a1, bfrag[gt][0], acc[gt][1][0]);
            acc[gt][1][1] = MFMA16(a1, bfrag[gt][1], acc[gt][1][1]);
        }
    }

    // K-split reduce: kw==1 waves dump accumulators, kw==0 waves add them (register-exact map)
    if (kw == 1) {
        float* dst = &red[bw * 4096];
#pragma unroll
        for (int gt = 0; gt < 4; ++gt)
#pragma unroll
            for (int fm = 0; fm < 2; ++fm)
#pragma unroll
                for (int fn = 0; fn < 2; ++fn)
#pragma unroll
                    for (int r = 0; r < 4; ++r)
                        dst[((((gt * 2 + fm) * 2 + fn) * 4) + r) * 64 + lane] = acc[gt][fm][fn][r];
    }
    __syncthreads();
    if (kw == 0) {
        const float* src = &red[bw * 4096];
#pragma unroll
        for (int gt = 0; gt < 4; ++gt)
#pragma unroll
            for (int fm = 0; fm < 2; ++fm)
#pragma unroll
                for (int fn = 0; fn < 2; ++fn)
#pragma unroll
                    for (int r = 0; r < 4; ++r)
                        acc[gt][fm][fn][r] += src[((((gt * 2 + fm) * 2 + fn) * 4) + r) * 64 + lane];

        // epilogue: activations + state update
#pragma unroll
        for (int fm = 0; fm < 2; ++fm)
#pragma unroll
            for (int fn = 0; fn < 2; ++fn) {
                int colh = h0 + fn * 16 + lr;
                float bi = b_hh[colh];
                float bf_ = b_hh[HDIM + colh];
                float bg = b_hh[2 * HDIM + colh];
                float bo = b_hh[3 * HDIM + colh];
#pragma unroll
                for (int r = 0; r < 4; ++r) {
                    int row = b0 + fm * 16 + (lane >> 4) * 4 + r;
                    const float* xWr = xW + (size_t)row * G4;
                    float gi = acc[0][fm][fn][r] + xWr[colh] + bi;
                    float gf = acc[1][fm][fn][r] + xWr[HDIM + colh] + bf_;
                    float gg = acc[2][fm][fn][r] + xWr[2 * HDIM + colh] + bg;
                    float go = acc[3][fm][fn][r] + xWr[3 * HDIM + colh] + bo;
                    float cc = c[(size_t)row * HDIM + colh];
                    float cn = sigmoid_f(gf) * cc + sigmoid_f(gi) * tanh_f(gg);
                    float hn = sigmoid_f(go) * tanh_f(cn);
                    c[(size_t)row * HDIM + colh] = cn;
                    h_out[(size_t)row * HDIM + colh] = (bf16)hn;
                }
            }
    }
}

// ---------------- launch ----------------
extern "C" void kernel_launch(void* const* d_in, const int* in_sizes, int n_in,
                              void* d_out, int out_size, void* d_ws, size_t ws_size,
                              hipStream_t stream) {
    const float* x    = (const float*)d_in[0];
    const float* h0   = (const float*)d_in[1];
    const float* c0   = (const float*)d_in[2];
    const float* W_ih = (const float*)d_in[3];
    const float* W_hh = (const float*)d_in[4];
    const float* b_ih = (const float*)d_in[5];
    const float* b_hh = (const float*)d_in[6];
    const float* W_out= (const float*)d_in[7];
    const float* b_out= (const float*)d_in[8];
    // d_in[9] = D = 64 (hardcoded)

    char* ws = (char*)d_ws;
    bf16*  Whh_b  = (bf16*)(ws + 0);                     // 8 MB
    bf16*  Wih_b  = (bf16*)(ws + (size_t)(8 << 20));     // 8 MB
    bf16*  x_b    = (bf16*)(ws + (size_t)(16 << 20));    // 1 MB
    bf16*  Wout_b = (bf16*)(ws + (size_t)(17 << 20));    // 1 MB
    float* xWbuf  = (float*)(ws + (size_t)(18 << 20));   // 8 MB
    float* cbuf   = (float*)(ws + (size_t)(26 << 20));   // 2 MB
    bf16*  h_all  = (bf16*)(ws + (size_t)(28 << 20));    // 65 MB (65 slots of 512x1024)

    const size_t HB = (size_t)BATCH * HDIM;  // elements per h slot

    prep_kernel<<<2048, 256, 0, stream>>>(x, h0, c0, W_ih, W_hh, W_out,
                                          x_b, Wih_b, Whh_b, Wout_b, h_all, cbuf);

    // xW = x @ W_ih^T + b_ih : M=512, N=4096, K=1024 -> 2048 wave-blocks
    gemm_bt<BATCH, G4, HDIM><<<2048, 64, 0, stream>>>(x_b, Wih_b, b_ih, xWbuf);

    for (int t = 0; t < DSTEP; ++t) {
        lstm_step<<<256, 256, 0, stream>>>(h_all + (size_t)t * HB, Whh_b, xWbuf, b_hh,
                                           cbuf, h_all + (size_t)(t + 1) * HB);
    }

    // outs = h_all[1..64] @ W_out^T + b_out : M=64*512=32768, N=512, K=1024 -> 16384 blocks
    gemm_bt<DSTEP * BATCH, NOUT, HDIM><<<16384, 64, 0, stream>>>(h_all + HB, Wout_b, b_out,
                                                                 (float*)d_out);
}